// Round 7
// baseline (113.769 us; speedup 1.0000x reference)
//
#include <hip/hip_runtime.h>

// emb[b,n,i] = cos(pi * i * x[b,n]),  i = 0..127
// rows = b*n = 1,048,576 ; out row-major [rows][128] f32 (512 MiB -> write-bound).
//
// cos(pi*i*x) = cos(2*pi*(i*x/2)); v_cos_f32 takes REVOLUTIONS:
// val = v_cos(fract(x/2 * i)) -- fract is exact period reduction.
//
// Round-7: fill-purity. The rocclr fill sustains 6.8 TB/s and its hot loop
// has ZERO loads -> no vmcnt waits ever. All our 5.2 TB/s variants kept a
// global x load near the loop (vmcnt shared by loads+stores; x is L3-evicted
// by the 512 MiB write stream -> ~900cy misses punch holes in the store
// stream). Here: block stages its 16 KiB x-chunk to LDS once, then each wave
// streams a contiguous 512 KiB output range; hot loop = 1 broadcast ds_read
// (depth-2 rotated, lgkmcnt only) + 4 cos + 1 nt store. Grid=256 (1 block/CU)
// matches the fill's few-long-streams geometry. Wave store = contiguous
// aligned 1 KiB (round-2 lesson: anything else doubles WRITE_SIZE).

typedef float f32x4 __attribute__((ext_vector_type(4)));

constexpr int ROWS_PER_WAVE  = 1024;                       // 4 KiB of x per wave
constexpr int WAVES_PER_BLK  = 4;
constexpr int ROWS_PER_BLK   = ROWS_PER_WAVE * WAVES_PER_BLK;  // 4096

__global__ __launch_bounds__(256) void Emb_37967510896970_kernel(
    const float* __restrict__ x, f32x4* __restrict__ out, int total_rows)
{
    __shared__ float xs[ROWS_PER_BLK];                     // 16 KiB

    const int tid      = threadIdx.x;
    const int blk_row0 = blockIdx.x * ROWS_PER_BLK;

    // stage this block's x chunk: 4096 floats via 4 coalesced float4/thread
    {
        const float4* xv = (const float4*)x + (blk_row0 >> 2);
        float4*       sv = (float4*)xs;
#pragma unroll
        for (int j = 0; j < 4; ++j) {
            int idx = j * 256 + tid;                       // float4 idx in chunk
            int r   = blk_row0 + idx * 4;
            float4 t = {0.f, 0.f, 0.f, 0.f};
            if (r < total_rows) t = xv[idx];
            sv[idx] = t;
        }
    }
    __syncthreads();

    const int wave = tid >> 6;
    const int lane = tid & 63;
    const int slot = lane & 31;                 // float4 slot within row
    const int rsel = lane >> 5;                 // which row of the pair
    const float i0 = (float)(slot << 2);

    const int    wrow0 = wave * ROWS_PER_WAVE;  // within block
    const float* xw    = xs + wrow0;
    f32x4*       p     = out + (size_t)(blk_row0 + wrow0) * 32 + lane;
    int          grow  = blk_row0 + wrow0 + rsel;   // this lane's global row

    constexpr int ITERS = ROWS_PER_WAVE / 2;    // 512: 2 rows (1 KiB) per iter

    // depth-2 rotated broadcast LDS reads (2 addresses/wave: conflict-free)
    float hA = 0.5f * xw[0 + rsel];
    float hB = 0.5f * xw[2 + rsel];

#pragma unroll 4
    for (int t = 0; t < ITERS; ++t) {
        int   tn = t + 2;
        float hC = 0.5f * xw[((tn < ITERS) ? 2 * tn : 0) + rsel];

        const float hb = hA * i0;
        f32x4 v;
#pragma unroll
        for (int k = 0; k < 4; ++k)
            v[k] = __builtin_amdgcn_cosf(
                       __builtin_amdgcn_fractf(fmaf(hA, (float)k, hb)));
        if (grow < total_rows)
            __builtin_nontemporal_store(v, p);

        p    += 64;                              // next row pair (1 KiB)
        grow += 2;
        hA = hB; hB = hC;
    }
}

extern "C" void kernel_launch(void* const* d_in, const int* in_sizes, int n_in,
                              void* d_out, int out_size, void* d_ws, size_t ws_size,
                              hipStream_t stream) {
    const float* x = (const float*)d_in[0];
    f32x4* out = (f32x4*)d_out;
    const int total_rows = in_sizes[0];                      // 1,048,576
    const int grid = (total_rows + ROWS_PER_BLK - 1) / ROWS_PER_BLK;  // 256
    Emb_37967510896970_kernel<<<grid, 256, 0, stream>>>(x, out, total_rows);
}